// Round 13
// baseline (40.886 us; speedup 1.0000x reference)
//
#include <hip/hip_runtime.h>
#include <math.h>

// SpatialDistanceGraph — MI355X, round 13: R12 with contention-free flag
// barriers (per-WG flag stores + parallel 16-lane poll; no shared atomic).
//
// DEAD-CODE NOTE (verified passing rounds 1-12): the EMD/Sinkhorn adjacency
// feeds only `where(softmax(adj)==0, -inf, attn)`; softmax output is never
// exactly 0 here (row logit spread << 87), so bb_coords and the Sinkhorn loop
// are dead. Computed pipeline:
//   x = LN(feat @ w_embed + b_embed; g1,b1)
//   3x GAT: h = x@Wl+bl; attn = softmax(h h^T / 16); o = attn@h;
//           x = elu(LN(o; gl,btl)); attn recorded
//   out = LN(x @ w_out + b_out; g2,b2); final_attention = mean(attns)
//
// R12 post-mortem: algebraic LN-fold moved nothing -> residual is the sync
// mechanism + launch overhead. R13: grid barrier arrivals become plain
// relaxed write-through stores to 16 INDEPENDENT flag addresses (no L3
// atomic serialization); the wait is 16 lanes polling all 16 flags with one
// vector load per iteration. Everything else identical to R12.
// Coherence protocol (proven R6-R12): relaxed agent-scope write-through
// publish + cached first-touch consume; vmcnt(0) before arrive; flags zeroed
// by in-graph hipMemsetAsync.

#define NWG 16

__device__ __forceinline__ void astore(float* p, float v) {
  __hip_atomic_store(p, v, __ATOMIC_RELAXED, __HIP_MEMORY_SCOPE_AGENT);
}

__device__ __forceinline__ void bar_arrive(int* flags, int slot, int w) {
  asm volatile("s_waitcnt vmcnt(0)" ::: "memory");
  __syncthreads();
  if (threadIdx.x == 0)
    __hip_atomic_store(&flags[slot * NWG + w], 1, __ATOMIC_RELAXED,
                       __HIP_MEMORY_SCOPE_AGENT);
}

__device__ __forceinline__ void bar_wait(int* flags, int slot) {
  if (threadIdx.x < NWG) {
    while (__hip_atomic_load(&flags[slot * NWG + threadIdx.x],
                             __ATOMIC_RELAXED,
                             __HIP_MEMORY_SCOPE_AGENT) == 0)
      __builtin_amdgcn_s_sleep(1);
  }
  __syncthreads();
  asm volatile("" ::: "memory");
}

__global__ __launch_bounds__(1024) void sdg_fused(
    const float* __restrict__ feat, const float* __restrict__ w_embed,
    const float* __restrict__ b_embed, const float* __restrict__ g1,
    const float* __restrict__ b1, const float* __restrict__ gat_W,
    const float* __restrict__ gat_b, const float* __restrict__ gat_g,
    const float* __restrict__ gat_bt, const float* __restrict__ w_out,
    const float* __restrict__ b_out, const float* __restrict__ g2,
    const float* __restrict__ b2, float* __restrict__ out, int* flags,
    float* __restrict__ e_ws, float* __restrict__ h_ws,
    float* __restrict__ gp_ws, float* __restrict__ st1_ws,
    float* __restrict__ st2_ws) {
  const int w = blockIdx.x, tid = threadIdx.x;
  const int w16 = w * 16, w48 = w * 48;
  const int c = tid & 15;           // col in slice
  const int ksl = (tid >> 4) & 15;  // k slice (16)
  const int rg = tid >> 8;          // row group (4)
  const int t2 = tid & 255;         // column index for PV/elu

  __shared__ __align__(16) float SA[14592];  // W: [768][19] / [256][19] / 3x
  __shared__ __align__(16) float SB[10752];  // Fs[14][768]; then Xs[14][260]
  __shared__ __align__(16) float Pb[3600];   // partials [16][225]
  __shared__ float Hb[240];                  // own h block [14][17]
  __shared__ float Gm[224];                  // UNSCALED Gram [14][16]
  __shared__ float Asm[224];                 // probs [14][16], cols 14/15 = 0
  __shared__ float aRow[224];                // attn accumulator
  __shared__ float hm[16];                   // h row means (pads 0)
  __shared__ float Ov[686];                  // own out cols [14][49]
  __shared__ float Mn[14], Rs[14], ps[14], psq[14];

  float* const Fs = SB;  // [14][768] during embed
  float* const Xs = SB;  // [14][260] afterwards

  // ---- stage embed weights -> SA[768][19] + feat ----
#pragma unroll
  for (int i = 0; i < 3; ++i) {
    const int idx = i * 1024 + tid;  // 3072 float4 slots
    const int k = idx >> 2, q = (idx & 3) * 4;
    const float4 v = *(const float4*)(&w_embed[k * 256 + w16 + q]);
    SA[k * 19 + q + 0] = v.x;
    SA[k * 19 + q + 1] = v.y;
    SA[k * 19 + q + 2] = v.z;
    SA[k * 19 + q + 3] = v.w;
  }
  for (int i = tid; i < 2688; i += 1024)
    *(float4*)(&Fs[i * 4]) = ((const float4*)feat)[i];
  if (tid < 224) aRow[tid] = 0.f;
  if (tid < 28) Asm[(tid >> 1) * 16 + 14 + (tid & 1)] = 0.f;  // pad cols
  if (tid < 2) hm[14 + tid] = 0.f;
  __syncthreads();

  // ---- S0: embed GEMM (4 rows x 48 k x 16 cols per thread) ----
  {
    float acc[4] = {0.f, 0.f, 0.f, 0.f};
    const int r0 = rg * 4, kb = ksl * 48;
#pragma unroll
    for (int ch = 0; ch < 12; ++ch) {
      const int k = kb + ch * 4;
      const float w0 = SA[(k + 0) * 19 + c];
      const float w1 = SA[(k + 1) * 19 + c];
      const float w2 = SA[(k + 2) * 19 + c];
      const float w3 = SA[(k + 3) * 19 + c];
#pragma unroll
      for (int rr = 0; rr < 4; ++rr) {
        const int r = r0 + rr;
        if (r < 14) {
          const float4 xv = *(const float4*)(&Fs[r * 768 + k]);
          acc[rr] = fmaf(
              xv.x, w0, fmaf(xv.y, w1, fmaf(xv.z, w2, fmaf(xv.w, w3, acc[rr]))));
        }
      }
    }
#pragma unroll
    for (int rr = 0; rr < 4; ++rr) {
      const int r = r0 + rr;
      if (r < 14) Pb[ksl * 225 + r * 16 + c] = acc[rr];
    }
  }
  __syncthreads();
  // column reduce + publish e + LN1 partial stats (16-col sum/sumsq)
  if (tid < 224) {
    const int r = tid >> 4, cc = tid & 15;
    float v = b_embed[w16 + cc];
#pragma unroll
    for (int q = 0; q < 16; ++q) v += Pb[q * 225 + tid];
    astore(&e_ws[r * 256 + w16 + cc], v);
    float sv = v, sq = v * v;
#pragma unroll
    for (int off = 8; off; off >>= 1) {
      sv += __shfl_xor(sv, off, 16);
      sq += __shfl_xor(sq, off, 16);
    }
    if (cc == 0) {
      astore(&st1_ws[w * 28 + r], sv);
      astore(&st1_ws[w * 28 + 14 + r], sq);
    }
  }
  bar_arrive(flags, 0, w);
  // stage layer-0 GAT weights [256][19] under the barrier wait
  {
    const int k = tid >> 2, q = (tid & 3) * 4;
    const float4 v = *(const float4*)(&gat_W[k * 256 + w16 + q]);
    SA[k * 19 + q + 0] = v.x;
    SA[k * 19 + q + 1] = v.y;
    SA[k * 19 + q + 2] = v.z;
    SA[k * 19 + q + 3] = v.w;
  }
  bar_wait(flags, 0);

  // ---- LN1 from stats (widened consume) + stage e -> Xs ----
  if (tid < 224) {
    const int r = tid >> 4, seg = tid & 15;
    float S = st1_ws[seg * 28 + r];
    float Q = st1_ws[seg * 28 + 14 + r];
#pragma unroll
    for (int off = 8; off; off >>= 1) {
      S += __shfl_xor(S, off, 16);
      Q += __shfl_xor(Q, off, 16);
    }
    if (seg == 0) {
      const float m = S * (1.f / 256.f);
      Mn[r] = m;
      Rs[r] = rsqrtf(Q * (1.f / 256.f) - m * m + 1e-5f);
    }
  }
  if (tid < 896) {
    const float4 v = ((const float4*)e_ws)[tid];
    const int idx = tid * 4, r = idx >> 8, cc = idx & 255;
    *(float4*)(&Xs[r * 260 + cc]) = v;
  }
  __syncthreads();
  for (int i = tid; i < 3584; i += 1024) {
    const int r = i >> 8, cc = i & 255;
    Xs[r * 260 + cc] = (Xs[r * 260 + cc] - Mn[r]) * Rs[r] * g1[cc] + b1[cc];
  }
  __syncthreads();

  // ---- 3 GAT layers, one barrier each ----
  for (int l = 0; l < 3; ++l) {
    // GEMM: 4 rows x 16 k x 16 cols per thread
    {
      float acc[4] = {0.f, 0.f, 0.f, 0.f};
      const int r0 = rg * 4, kb = ksl * 16;
#pragma unroll
      for (int ch = 0; ch < 4; ++ch) {
        const int k = kb + ch * 4;
        const float w0 = SA[(k + 0) * 19 + c];
        const float w1 = SA[(k + 1) * 19 + c];
        const float w2 = SA[(k + 2) * 19 + c];
        const float w3 = SA[(k + 3) * 19 + c];
#pragma unroll
        for (int rr = 0; rr < 4; ++rr) {
          const int r = r0 + rr;
          if (r < 14) {
            const float4 xv = *(const float4*)(&Xs[r * 260 + k]);
            acc[rr] = fmaf(
                xv.x, w0,
                fmaf(xv.y, w1, fmaf(xv.z, w2, fmaf(xv.w, w3, acc[rr]))));
          }
        }
      }
#pragma unroll
      for (int rr = 0; rr < 4; ++rr) {
        const int r = r0 + rr;
        if (r < 14) Pb[ksl * 225 + r * 16 + c] = acc[rr];
      }
    }
    __syncthreads();
    // reduce + publish h + h row-sum partial (for mean identity)
    if (tid < 224) {
      const int r = tid >> 4, cc = tid & 15;
      float v = gat_b[l * 256 + w16 + cc];
#pragma unroll
      for (int q = 0; q < 16; ++q) v += Pb[q * 225 + tid];
      Hb[r * 17 + cc] = v;
      astore(&h_ws[l * 3584 + r * 256 + w16 + cc], v);
      float sv = v;
#pragma unroll
      for (int off = 8; off; off >>= 1) sv += __shfl_xor(sv, off, 16);
      if (cc == 0) astore(&gp_ws[l * 3584 + w * 224 + 196 + r], sv);
    }
    __syncthreads();
    // partial Gram over own 16 cols
    if (tid < 196) {
      const int i = tid / 14, j = tid - i * 14;
      float s = 0.f;
#pragma unroll
      for (int cc = 0; cc < 16; ++cc)
        s = fmaf(Hb[i * 17 + cc], Hb[j * 17 + cc], s);
      astore(&gp_ws[l * 3584 + w * 224 + tid], s);
    }
    bar_arrive(flags, 1 + l, w);
    // stage next-stage weights into SA under the barrier wait
    if (l < 2) {
      const float* Wn = gat_W + (l + 1) * 65536;
      const int k = tid >> 2, q = (tid & 3) * 4;
      const float4 v = *(const float4*)(&Wn[k * 256 + w16 + q]);
      SA[k * 19 + q + 0] = v.x;
      SA[k * 19 + q + 1] = v.y;
      SA[k * 19 + q + 2] = v.z;
      SA[k * 19 + q + 3] = v.w;
    } else {
#pragma unroll
      for (int g = 0; g < 3; ++g) {
        const int k = tid >> 2, q = (tid & 3) * 4;
        const float4 v = *(const float4*)(&w_out[k * 768 + w48 + g * 16 + q]);
        SA[g * 4864 + k * 19 + q + 0] = v.x;
        SA[g * 4864 + k * 19 + q + 1] = v.y;
        SA[g * 4864 + k * 19 + q + 2] = v.z;
        SA[g * 4864 + k * 19 + q + 3] = v.w;
      }
    }
    bar_wait(flags, 1 + l);

    // issue PV h loads FIRST (in flight during consume + softmax)
    float hv[16];
    hv[14] = 0.f;
    hv[15] = 0.f;
#pragma unroll
    for (int m = 0; m < 14; ++m) hv[m] = h_ws[l * 3584 + m * 256 + t2];
    // consume Gram partials + h row-sums
    if (tid < 196) {
      float s = 0.f;
      const float* gpl = gp_ws + l * 3584 + tid;
#pragma unroll
      for (int ww = 0; ww < 16; ++ww) s += gpl[ww * 224];
      const int i = tid / 14, j = tid - i * 14;
      Gm[i * 16 + j] = s;             // unscaled Gram
      Asm[i * 16 + j] = s * 0.0625f;  // logits; adj-mask never fires
    } else if (tid < 210) {
      const int m = tid - 196;
      float s = 0.f;
      const float* gpl = gp_ws + l * 3584 + 196 + m;
#pragma unroll
      for (int ww = 0; ww < 16; ++ww) s += gpl[ww * 224];
      hm[m] = s * (1.f / 256.f);
    }
    __syncthreads();
    // wave-parallel softmax (16-lane groups)
    if (tid < 224) {
      const int r = tid >> 4, j = tid & 15;
      const float lv = (j < 14) ? Asm[r * 16 + j] : -1e30f;
      float mx = lv;
#pragma unroll
      for (int off = 8; off; off >>= 1) mx = fmaxf(mx, __shfl_xor(mx, off, 16));
      float p = (j < 14) ? expf(lv - mx) : 0.f;
      float sm = p;
#pragma unroll
      for (int off = 8; off; off >>= 1) sm += __shfl_xor(sm, off, 16);
      p /= sm;
      if (j < 14) {
        Asm[r * 16 + j] = p;
        aRow[r * 16 + j] += p * (1.f / 3.f);
      }
    }
    __syncthreads();
    // PV (all threads) + LN stats from A,G,hm (224 threads, concurrent)
    float o[4] = {0.f, 0.f, 0.f, 0.f};
#pragma unroll
    for (int mc = 0; mc < 4; ++mc) {
#pragma unroll
      for (int rr = 0; rr < 4; ++rr) {
        const int r = rg * 4 + rr;
        if (r < 14) {
          const float4 a = *(const float4*)(&Asm[r * 16 + mc * 4]);
          o[rr] = fmaf(a.x, hv[mc * 4 + 0],
                       fmaf(a.y, hv[mc * 4 + 1],
                            fmaf(a.z, hv[mc * 4 + 2],
                                 fmaf(a.w, hv[mc * 4 + 3], o[rr]))));
        }
      }
    }
    if (tid < 224) {
      const int r = tid >> 4, j = tid & 15;
      const float aj = Asm[r * 16 + j];  // pads are 0
      float tq = 0.f;
      if (j < 14) {
#pragma unroll
        for (int i = 0; i < 14; ++i)
          tq = fmaf(Asm[r * 16 + i], Gm[i * 16 + j], tq);
      }
      float qv = tq * aj;     // A^T G A partial
      float mv = aj * hm[j];  // mean partial
#pragma unroll
      for (int off = 8; off; off >>= 1) {
        qv += __shfl_xor(qv, off, 16);
        mv += __shfl_xor(mv, off, 16);
      }
      if (j == 0) {
        Mn[r] = mv;
        Rs[r] = rsqrtf(qv * (1.f / 256.f) - mv * mv + 1e-5f);
      }
    }
    __syncthreads();
    // LN + elu directly on registers -> Xs
    {
      const float gc = gat_g[l * 256 + t2], bc = gat_bt[l * 256 + t2];
#pragma unroll
      for (int rr = 0; rr < 4; ++rr) {
        const int r = rg * 4 + rr;
        if (r < 14) {
          const float xn = (o[rr] - Mn[r]) * Rs[r] * gc + bc;
          Xs[r * 260 + t2] = xn > 0.f ? xn : expm1f(xn);
        }
      }
      if (l == 2) {
        if (w < 14 && tid < 14)
          out[10752 + w * 14 + tid] = aRow[w * 16 + tid];  // final_attention
        if (tid < 14) {
          ps[tid] = 0.f;
          psq[tid] = 0.f;
        }
      }
    }
    __syncthreads();
  }

  // ---- S4: out GEMM (3 groups of 16 cols) + folded LN768 stats ----
  for (int g = 0; g < 3; ++g) {
    {
      float acc[4] = {0.f, 0.f, 0.f, 0.f};
      const int r0 = rg * 4, kb = ksl * 16;
#pragma unroll
      for (int ch = 0; ch < 4; ++ch) {
        const int k = kb + ch * 4;
        const float w0 = SA[g * 4864 + (k + 0) * 19 + c];
        const float w1 = SA[g * 4864 + (k + 1) * 19 + c];
        const float w2 = SA[g * 4864 + (k + 2) * 19 + c];
        const float w3 = SA[g * 4864 + (k + 3) * 19 + c];
#pragma unroll
        for (int rr = 0; rr < 4; ++rr) {
          const int r = r0 + rr;
          if (r < 14) {
            const float4 xv = *(const float4*)(&Xs[r * 260 + k]);
            acc[rr] = fmaf(
                xv.x, w0,
                fmaf(xv.y, w1, fmaf(xv.z, w2, fmaf(xv.w, w3, acc[rr]))));
          }
        }
      }
#pragma unroll
      for (int rr = 0; rr < 4; ++rr) {
        const int r = r0 + rr;
        if (r < 14) Pb[ksl * 225 + r * 16 + c] = acc[rr];
      }
    }
    __syncthreads();
    if (tid < 224) {
      const int r = tid >> 4, cc = tid & 15;
      float v = b_out[w48 + g * 16 + cc];
#pragma unroll
      for (int q = 0; q < 16; ++q) v += Pb[q * 225 + tid];
      Ov[r * 49 + g * 16 + cc] = v;
      float sv = v, sq = v * v;
#pragma unroll
      for (int off = 8; off; off >>= 1) {
        sv += __shfl_xor(sv, off, 16);
        sq += __shfl_xor(sq, off, 16);
      }
      if (cc == 0) {
        ps[r] += sv;
        psq[r] += sq;
      }
    }
    __syncthreads();
  }
  if (tid < 14) {
    astore(&st2_ws[w * 28 + tid], ps[tid]);
    astore(&st2_ws[w * 28 + 14 + tid], psq[tid]);
  }
  bar_arrive(flags, 4, w);
  bar_wait(flags, 4);
  // LN768 from stats (widened consume); write own 48 output columns
  if (tid < 224) {
    const int r = tid >> 4, seg = tid & 15;
    float S = st2_ws[seg * 28 + r];
    float Q = st2_ws[seg * 28 + 14 + r];
#pragma unroll
    for (int off = 8; off; off >>= 1) {
      S += __shfl_xor(S, off, 16);
      Q += __shfl_xor(Q, off, 16);
    }
    if (seg == 0) {
      const float m = S * (1.f / 768.f);
      Mn[r] = m;
      Rs[r] = rsqrtf(Q * (1.f / 768.f) - m * m + 1e-5f);
    }
  }
  __syncthreads();
  if (tid < 224) {
    const int r = tid >> 4, cc = tid & 15;
    const float m = Mn[r], rs = Rs[r];
#pragma unroll
    for (int g = 0; g < 3; ++g) {
      const int col = w48 + g * 16 + cc;
      out[r * 768 + col] =
          (Ov[r * 49 + g * 16 + cc] - m) * rs * g2[col] + b2[col];
    }
  }
}

extern "C" void kernel_launch(void* const* d_in, const int* in_sizes, int n_in,
                              void* d_out, int out_size, void* d_ws,
                              size_t ws_size, hipStream_t stream) {
  const float* feat = (const float*)d_in[0];
  // d_in[1] (bb_coords) provably does not influence the outputs — unused.
  const float* w_embed = (const float*)d_in[2];
  const float* b_embed = (const float*)d_in[3];
  const float* g1 = (const float*)d_in[4];
  const float* b1 = (const float*)d_in[5];
  const float* gat_W = (const float*)d_in[6];
  const float* gat_b = (const float*)d_in[7];
  const float* gat_g = (const float*)d_in[8];
  const float* gat_bt = (const float*)d_in[9];
  const float* w_out = (const float*)d_in[10];
  const float* b_out = (const float*)d_in[11];
  const float* g2 = (const float*)d_in[12];
  const float* b2 = (const float*)d_in[13];
  float* out = (float*)d_out;

  int* flags = (int*)d_ws;             // 5 * 16 flags (80 ints)
  float* e_ws = (float*)d_ws + 96;     // 3584
  float* h_ws = e_ws + 3584;           // 3 * 3584
  float* gp_ws = h_ws + 3 * 3584;      // 3 * 16 * 224 (196 gram + 14 hsum)
  float* st1_ws = gp_ws + 3 * 3584;    // 16 * 28 (LN1 stats)
  float* st2_ws = st1_ws + 448;        // 16 * 28 (LN768 stats)

  hipMemsetAsync(flags, 0, 96 * sizeof(int), stream);
  sdg_fused<<<NWG, 1024, 0, stream>>>(feat, w_embed, b_embed, g1, b1, gat_W,
                                      gat_b, gat_g, gat_bt, w_out, b_out, g2,
                                      b2, out, flags, e_ws, h_ws, gp_ws,
                                      st1_ws, st2_ws);
}

// Round 14
// 39.022 us; speedup vs baseline: 1.0478x; 1.0478x over previous
//
#include <hip/hip_runtime.h>
#include <math.h>

// SpatialDistanceGraph — MI355X, round 14: R13 protocol at 32 WGs x 8 cols
// (halves the largest serial stage: embed staging + embed GEMM).
//
// DEAD-CODE NOTE (verified passing rounds 1-13): the EMD/Sinkhorn adjacency
// feeds only `where(softmax(adj)==0, -inf, attn)`; softmax output is never
// exactly 0 here (row logit spread << 87), so bb_coords and the Sinkhorn loop
// are dead. Computed pipeline:
//   x = LN(feat @ w_embed + b_embed; g1,b1)
//   3x GAT: h = x@Wl+bl; attn = softmax(h h^T / 16); o = attn@h;
//           x = elu(LN(o; gl,btl)); attn recorded
//   out = LN(x @ w_out + b_out; g2,b2); final_attention = mean(attns)
//
// R13 post-mortem: flag barriers null -> barrier mechanism exonerated; all
// of {traffic, LDS-issue, TLP, compute chain, barrier} nulled. Largest
// remaining serial stage = embed staging+GEMM (~6-8us). R14: 32 WGs each own
// 8 columns (24 for w_out): per-WG weight slice and embed GEMM halve; all
// consume loops widen to 32 partials (independent loads). Protocol unchanged
// (proven R6-R13): relaxed agent-scope write-through publish + cached
// first-touch consume; per-WG flag barriers; flags zeroed via memsetAsync.

#define NWG 32

__device__ __forceinline__ void astore(float* p, float v) {
  __hip_atomic_store(p, v, __ATOMIC_RELAXED, __HIP_MEMORY_SCOPE_AGENT);
}

__device__ __forceinline__ void bar_arrive(int* flags, int slot, int w) {
  asm volatile("s_waitcnt vmcnt(0)" ::: "memory");
  __syncthreads();
  if (threadIdx.x == 0)
    __hip_atomic_store(&flags[slot * NWG + w], 1, __ATOMIC_RELAXED,
                       __HIP_MEMORY_SCOPE_AGENT);
}

__device__ __forceinline__ void bar_wait(int* flags, int slot) {
  if (threadIdx.x < NWG) {
    while (__hip_atomic_load(&flags[slot * NWG + threadIdx.x],
                             __ATOMIC_RELAXED,
                             __HIP_MEMORY_SCOPE_AGENT) == 0)
      __builtin_amdgcn_s_sleep(1);
  }
  __syncthreads();
  asm volatile("" ::: "memory");
}

__global__ __launch_bounds__(1024) void sdg_fused(
    const float* __restrict__ feat, const float* __restrict__ w_embed,
    const float* __restrict__ b_embed, const float* __restrict__ g1,
    const float* __restrict__ b1, const float* __restrict__ gat_W,
    const float* __restrict__ gat_b, const float* __restrict__ gat_g,
    const float* __restrict__ gat_bt, const float* __restrict__ w_out,
    const float* __restrict__ b_out, const float* __restrict__ g2,
    const float* __restrict__ b2, float* __restrict__ out, int* flags,
    float* __restrict__ e_ws, float* __restrict__ h_ws,
    float* __restrict__ gp_ws, float* __restrict__ st1_ws,
    float* __restrict__ st2_ws) {
  const int w = blockIdx.x, tid = threadIdx.x;
  const int w8 = w * 8, w24 = w * 24;
  const int c = tid & 7;           // col in slice (8)
  const int ksl = (tid >> 3) & 31; // k slice (32)
  const int rg = tid >> 8;         // row group (4)
  const int t2 = tid & 255;        // column index for PV/elu

  __shared__ __align__(16) float SA[6912];   // W: [768][9] / [256][9] / 3x
  __shared__ __align__(16) float SB[10752];  // Fs[14][768]; then Xs[14][260]
  __shared__ __align__(16) float Pb[3616];   // partials [32][113]
  __shared__ float Hb[126];                  // own h block [14][9]
  __shared__ float Gm[224];                  // UNSCALED Gram [14][16]
  __shared__ float Asm[224];                 // probs [14][16], cols 14/15 = 0
  __shared__ float aRow[224];                // attn accumulator
  __shared__ float hm[16];                   // h row means (pads 0)
  __shared__ float Ov[350];                  // own out cols [14][25]
  __shared__ float Mn[14], Rs[14], ps[14], psq[14];

  float* const Fs = SB;  // [14][768] during embed
  float* const Xs = SB;  // [14][260] afterwards

  // ---- stage embed weights -> SA[768][9] + feat ----
#pragma unroll
  for (int i = 0; i < 2; ++i) {
    const int idx = i * 1024 + tid;  // 1536 float4 slots
    if (idx < 1536) {
      const int k = idx >> 1, q = (idx & 1) * 4;
      const float4 v = *(const float4*)(&w_embed[k * 256 + w8 + q]);
      SA[k * 9 + q + 0] = v.x;
      SA[k * 9 + q + 1] = v.y;
      SA[k * 9 + q + 2] = v.z;
      SA[k * 9 + q + 3] = v.w;
    }
  }
  for (int i = tid; i < 2688; i += 1024)
    *(float4*)(&Fs[i * 4]) = ((const float4*)feat)[i];
  if (tid < 224) aRow[tid] = 0.f;
  if (tid < 28) Asm[(tid >> 1) * 16 + 14 + (tid & 1)] = 0.f;  // pad cols
  if (tid < 2) hm[14 + tid] = 0.f;
  __syncthreads();

  // ---- S0: embed GEMM (4 rows x 24 k x 8 cols per thread) ----
  {
    float acc[4] = {0.f, 0.f, 0.f, 0.f};
    const int r0 = rg * 4, kb = ksl * 24;
#pragma unroll
    for (int ch = 0; ch < 6; ++ch) {
      const int k = kb + ch * 4;
      const float w0 = SA[(k + 0) * 9 + c];
      const float w1 = SA[(k + 1) * 9 + c];
      const float w2 = SA[(k + 2) * 9 + c];
      const float w3 = SA[(k + 3) * 9 + c];
#pragma unroll
      for (int rr = 0; rr < 4; ++rr) {
        const int r = r0 + rr;
        if (r < 14) {
          const float4 xv = *(const float4*)(&Fs[r * 768 + k]);
          acc[rr] = fmaf(
              xv.x, w0, fmaf(xv.y, w1, fmaf(xv.z, w2, fmaf(xv.w, w3, acc[rr]))));
        }
      }
    }
#pragma unroll
    for (int rr = 0; rr < 4; ++rr) {
      const int r = r0 + rr;
      if (r < 14) Pb[ksl * 113 + r * 8 + c] = acc[rr];
    }
  }
  __syncthreads();
  // column reduce + publish e + LN1 partial stats (8-col sum/sumsq)
  if (tid < 112) {
    const int r = tid >> 3, cc = tid & 7;
    float v = b_embed[w8 + cc];
#pragma unroll
    for (int q = 0; q < 32; ++q) v += Pb[q * 113 + tid];
    astore(&e_ws[r * 256 + w8 + cc], v);
    float sv = v, sq = v * v;
#pragma unroll
    for (int off = 4; off; off >>= 1) {
      sv += __shfl_xor(sv, off, 8);
      sq += __shfl_xor(sq, off, 8);
    }
    if (cc == 0) {
      astore(&st1_ws[w * 28 + r], sv);
      astore(&st1_ws[w * 28 + 14 + r], sq);
    }
  }
  bar_arrive(flags, 0, w);
  // stage layer-0 GAT weights [256][9] under the barrier wait
  if (tid < 512) {
    const int k = tid >> 1, q = (tid & 1) * 4;
    const float4 v = *(const float4*)(&gat_W[k * 256 + w8 + q]);
    SA[k * 9 + q + 0] = v.x;
    SA[k * 9 + q + 1] = v.y;
    SA[k * 9 + q + 2] = v.z;
    SA[k * 9 + q + 3] = v.w;
  }
  bar_wait(flags, 0);

  // ---- LN1 from stats (width-32 consume) + stage e -> Xs ----
  if (tid < 448) {
    const int r = tid >> 5, seg = tid & 31;
    float S = st1_ws[seg * 28 + r];
    float Q = st1_ws[seg * 28 + 14 + r];
#pragma unroll
    for (int off = 16; off; off >>= 1) {
      S += __shfl_xor(S, off, 32);
      Q += __shfl_xor(Q, off, 32);
    }
    if (seg == 0) {
      const float m = S * (1.f / 256.f);
      Mn[r] = m;
      Rs[r] = rsqrtf(Q * (1.f / 256.f) - m * m + 1e-5f);
    }
  }
  if (tid < 896) {
    const float4 v = ((const float4*)e_ws)[tid];
    const int idx = tid * 4, r = idx >> 8, cc = idx & 255;
    *(float4*)(&Xs[r * 260 + cc]) = v;
  }
  __syncthreads();
  for (int i = tid; i < 3584; i += 1024) {
    const int r = i >> 8, cc = i & 255;
    Xs[r * 260 + cc] = (Xs[r * 260 + cc] - Mn[r]) * Rs[r] * g1[cc] + b1[cc];
  }
  __syncthreads();

  // ---- 3 GAT layers, one barrier each ----
  for (int l = 0; l < 3; ++l) {
    // GEMM: 4 rows x 8 k x 8 cols per thread
    {
      float acc[4] = {0.f, 0.f, 0.f, 0.f};
      const int r0 = rg * 4, kb = ksl * 8;
#pragma unroll
      for (int ch = 0; ch < 2; ++ch) {
        const int k = kb + ch * 4;
        const float w0 = SA[(k + 0) * 9 + c];
        const float w1 = SA[(k + 1) * 9 + c];
        const float w2 = SA[(k + 2) * 9 + c];
        const float w3 = SA[(k + 3) * 9 + c];
#pragma unroll
        for (int rr = 0; rr < 4; ++rr) {
          const int r = r0 + rr;
          if (r < 14) {
            const float4 xv = *(const float4*)(&Xs[r * 260 + k]);
            acc[rr] = fmaf(
                xv.x, w0,
                fmaf(xv.y, w1, fmaf(xv.z, w2, fmaf(xv.w, w3, acc[rr]))));
          }
        }
      }
#pragma unroll
      for (int rr = 0; rr < 4; ++rr) {
        const int r = r0 + rr;
        if (r < 14) Pb[ksl * 113 + r * 8 + c] = acc[rr];
      }
    }
    __syncthreads();
    // reduce + publish h + h row-sum partial (for mean identity)
    if (tid < 112) {
      const int r = tid >> 3, cc = tid & 7;
      float v = gat_b[l * 256 + w8 + cc];
#pragma unroll
      for (int q = 0; q < 32; ++q) v += Pb[q * 113 + tid];
      Hb[r * 9 + cc] = v;
      astore(&h_ws[l * 3584 + r * 256 + w8 + cc], v);
      float sv = v;
#pragma unroll
      for (int off = 4; off; off >>= 1) sv += __shfl_xor(sv, off, 8);
      if (cc == 0) astore(&gp_ws[l * 7168 + w * 224 + 196 + r], sv);
    }
    __syncthreads();
    // partial Gram over own 8 cols
    if (tid < 196) {
      const int i = tid / 14, j = tid - i * 14;
      float s = 0.f;
#pragma unroll
      for (int cc = 0; cc < 8; ++cc)
        s = fmaf(Hb[i * 9 + cc], Hb[j * 9 + cc], s);
      astore(&gp_ws[l * 7168 + w * 224 + tid], s);
    }
    bar_arrive(flags, 1 + l, w);
    // stage next-stage weights into SA under the barrier wait
    if (l < 2) {
      if (tid < 512) {
        const float* Wn = gat_W + (l + 1) * 65536;
        const int k = tid >> 1, q = (tid & 1) * 4;
        const float4 v = *(const float4*)(&Wn[k * 256 + w8 + q]);
        SA[k * 9 + q + 0] = v.x;
        SA[k * 9 + q + 1] = v.y;
        SA[k * 9 + q + 2] = v.z;
        SA[k * 9 + q + 3] = v.w;
      }
    } else {
      if (tid < 512) {
        const int k = tid >> 1, q = (tid & 1) * 4;
#pragma unroll
        for (int g = 0; g < 3; ++g) {
          const float4 v = *(const float4*)(&w_out[k * 768 + w24 + g * 8 + q]);
          SA[g * 2304 + k * 9 + q + 0] = v.x;
          SA[g * 2304 + k * 9 + q + 1] = v.y;
          SA[g * 2304 + k * 9 + q + 2] = v.z;
          SA[g * 2304 + k * 9 + q + 3] = v.w;
        }
      }
    }
    bar_wait(flags, 1 + l);

    // issue PV h loads FIRST (in flight during consume + softmax)
    float hv[16];
    hv[14] = 0.f;
    hv[15] = 0.f;
#pragma unroll
    for (int m = 0; m < 14; ++m) hv[m] = h_ws[l * 3584 + m * 256 + t2];
    // consume Gram partials + h row-sums (32 independent loads each)
    if (tid < 196) {
      float s = 0.f;
      const float* gpl = gp_ws + l * 7168 + tid;
#pragma unroll
      for (int ww = 0; ww < 32; ++ww) s += gpl[ww * 224];
      const int i = tid / 14, j = tid - i * 14;
      Gm[i * 16 + j] = s;             // unscaled Gram
      Asm[i * 16 + j] = s * 0.0625f;  // logits; adj-mask never fires
    } else if (tid < 210) {
      const int m = tid - 196;
      float s = 0.f;
      const float* gpl = gp_ws + l * 7168 + 196 + m;
#pragma unroll
      for (int ww = 0; ww < 32; ++ww) s += gpl[ww * 224];
      hm[m] = s * (1.f / 256.f);
    }
    __syncthreads();
    // wave-parallel softmax (16-lane groups)
    if (tid < 224) {
      const int r = tid >> 4, j = tid & 15;
      const float lv = (j < 14) ? Asm[r * 16 + j] : -1e30f;
      float mx = lv;
#pragma unroll
      for (int off = 8; off; off >>= 1) mx = fmaxf(mx, __shfl_xor(mx, off, 16));
      float p = (j < 14) ? expf(lv - mx) : 0.f;
      float sm = p;
#pragma unroll
      for (int off = 8; off; off >>= 1) sm += __shfl_xor(sm, off, 16);
      p /= sm;
      if (j < 14) {
        Asm[r * 16 + j] = p;
        aRow[r * 16 + j] += p * (1.f / 3.f);
      }
    }
    __syncthreads();
    // PV (all threads) + LN stats from A,G,hm (224 threads, concurrent)
    float o[4] = {0.f, 0.f, 0.f, 0.f};
#pragma unroll
    for (int mc = 0; mc < 4; ++mc) {
#pragma unroll
      for (int rr = 0; rr < 4; ++rr) {
        const int r = rg * 4 + rr;
        if (r < 14) {
          const float4 a = *(const float4*)(&Asm[r * 16 + mc * 4]);
          o[rr] = fmaf(a.x, hv[mc * 4 + 0],
                       fmaf(a.y, hv[mc * 4 + 1],
                            fmaf(a.z, hv[mc * 4 + 2],
                                 fmaf(a.w, hv[mc * 4 + 3], o[rr]))));
        }
      }
    }
    if (tid < 224) {
      const int r = tid >> 4, j = tid & 15;
      const float aj = Asm[r * 16 + j];  // pads are 0
      float tq = 0.f;
      if (j < 14) {
#pragma unroll
        for (int i = 0; i < 14; ++i)
          tq = fmaf(Asm[r * 16 + i], Gm[i * 16 + j], tq);
      }
      float qv = tq * aj;     // A^T G A partial
      float mv = aj * hm[j];  // mean partial
#pragma unroll
      for (int off = 8; off; off >>= 1) {
        qv += __shfl_xor(qv, off, 16);
        mv += __shfl_xor(mv, off, 16);
      }
      if (j == 0) {
        Mn[r] = mv;
        Rs[r] = rsqrtf(qv * (1.f / 256.f) - mv * mv + 1e-5f);
      }
    }
    __syncthreads();
    // LN + elu directly on registers -> Xs
    {
      const float gc = gat_g[l * 256 + t2], bc = gat_bt[l * 256 + t2];
#pragma unroll
      for (int rr = 0; rr < 4; ++rr) {
        const int r = rg * 4 + rr;
        if (r < 14) {
          const float xn = (o[rr] - Mn[r]) * Rs[r] * gc + bc;
          Xs[r * 260 + t2] = xn > 0.f ? xn : expm1f(xn);
        }
      }
      if (l == 2) {
        if (w < 14 && tid < 14)
          out[10752 + w * 14 + tid] = aRow[w * 16 + tid];  // final_attention
        if (tid < 14) {
          ps[tid] = 0.f;
          psq[tid] = 0.f;
        }
      }
    }
    __syncthreads();
  }

  // ---- S4: out GEMM (3 groups of 8 cols) + folded LN768 stats ----
  for (int g = 0; g < 3; ++g) {
    {
      float acc[4] = {0.f, 0.f, 0.f, 0.f};
      const int r0 = rg * 4, kb = ksl * 8;
#pragma unroll
      for (int ch = 0; ch < 2; ++ch) {
        const int k = kb + ch * 4;
        const float w0 = SA[g * 2304 + (k + 0) * 9 + c];
        const float w1 = SA[g * 2304 + (k + 1) * 9 + c];
        const float w2 = SA[g * 2304 + (k + 2) * 9 + c];
        const float w3 = SA[g * 2304 + (k + 3) * 9 + c];
#pragma unroll
        for (int rr = 0; rr < 4; ++rr) {
          const int r = r0 + rr;
          if (r < 14) {
            const float4 xv = *(const float4*)(&Xs[r * 260 + k]);
            acc[rr] = fmaf(
                xv.x, w0,
                fmaf(xv.y, w1, fmaf(xv.z, w2, fmaf(xv.w, w3, acc[rr]))));
          }
        }
      }
#pragma unroll
      for (int rr = 0; rr < 4; ++rr) {
        const int r = r0 + rr;
        if (r < 14) Pb[ksl * 113 + r * 8 + c] = acc[rr];
      }
    }
    __syncthreads();
    if (tid < 112) {
      const int r = tid >> 3, cc = tid & 7;
      float v = b_out[w24 + g * 8 + cc];
#pragma unroll
      for (int q = 0; q < 32; ++q) v += Pb[q * 113 + tid];
      Ov[r * 25 + g * 8 + cc] = v;
      float sv = v, sq = v * v;
#pragma unroll
      for (int off = 4; off; off >>= 1) {
        sv += __shfl_xor(sv, off, 8);
        sq += __shfl_xor(sq, off, 8);
      }
      if (cc == 0) {
        ps[r] += sv;
        psq[r] += sq;
      }
    }
    __syncthreads();
  }
  if (tid < 14) {
    astore(&st2_ws[w * 28 + tid], ps[tid]);
    astore(&st2_ws[w * 28 + 14 + tid], psq[tid]);
  }
  bar_arrive(flags, 4, w);
  bar_wait(flags, 4);
  // LN768 from stats (width-32 consume); write own 24 output columns
  if (tid < 448) {
    const int r = tid >> 5, seg = tid & 31;
    float S = st2_ws[seg * 28 + r];
    float Q = st2_ws[seg * 28 + 14 + r];
#pragma unroll
    for (int off = 16; off; off >>= 1) {
      S += __shfl_xor(S, off, 32);
      Q += __shfl_xor(Q, off, 32);
    }
    if (seg == 0) {
      const float m = S * (1.f / 768.f);
      Mn[r] = m;
      Rs[r] = rsqrtf(Q * (1.f / 768.f) - m * m + 1e-5f);
    }
  }
  __syncthreads();
  if (tid < 112) {
    const int r = tid >> 3, cc = tid & 7;
    const float m = Mn[r], rs = Rs[r];
#pragma unroll
    for (int g = 0; g < 3; ++g) {
      const int col = w24 + g * 8 + cc;
      out[r * 768 + col] =
          (Ov[r * 25 + g * 8 + cc] - m) * rs * g2[col] + b2[col];
    }
  }
}

extern "C" void kernel_launch(void* const* d_in, const int* in_sizes, int n_in,
                              void* d_out, int out_size, void* d_ws,
                              size_t ws_size, hipStream_t stream) {
  const float* feat = (const float*)d_in[0];
  // d_in[1] (bb_coords) provably does not influence the outputs — unused.
  const float* w_embed = (const float*)d_in[2];
  const float* b_embed = (const float*)d_in[3];
  const float* g1 = (const float*)d_in[4];
  const float* b1 = (const float*)d_in[5];
  const float* gat_W = (const float*)d_in[6];
  const float* gat_b = (const float*)d_in[7];
  const float* gat_g = (const float*)d_in[8];
  const float* gat_bt = (const float*)d_in[9];
  const float* w_out = (const float*)d_in[10];
  const float* b_out = (const float*)d_in[11];
  const float* g2 = (const float*)d_in[12];
  const float* b2 = (const float*)d_in[13];
  float* out = (float*)d_out;

  int* flags = (int*)d_ws;             // 5 * 32 flags (160 ints, pad 192)
  float* e_ws = (float*)d_ws + 192;    // 3584
  float* h_ws = e_ws + 3584;           // 3 * 3584
  float* gp_ws = h_ws + 3 * 3584;      // 3 * 32 * 224 (196 gram + 14 hsum)
  float* st1_ws = gp_ws + 3 * 7168;    // 32 * 28 (LN1 stats)
  float* st2_ws = st1_ws + 896;        // 32 * 28 (LN768 stats)

  hipMemsetAsync(flags, 0, 192 * sizeof(int), stream);
  sdg_fused<<<NWG, 1024, 0, stream>>>(feat, w_embed, b_embed, g1, b1, gat_W,
                                      gat_b, gat_g, gat_bt, w_out, b_out, g2,
                                      b2, out, flags, e_ws, h_ws, gp_ws,
                                      st1_ws, st2_ws);
}

// Round 15
// 36.355 us; speedup vs baseline: 1.1246x; 1.0733x over previous
//
#include <hip/hip_runtime.h>
#include <math.h>

// SpatialDistanceGraph — MI355X, round 15: R14 + fused consume/softmax
// (16-lane-group relayout, no LDS round-trip) + single-pass out-GEMM.
//
// DEAD-CODE NOTE (verified passing rounds 1-14): the EMD/Sinkhorn adjacency
// feeds only `where(softmax(adj)==0, -inf, attn)`; softmax output is never
// exactly 0 here (row logit spread << 87), so bb_coords and the Sinkhorn loop
// are dead. Computed pipeline:
//   x = LN(feat @ w_embed + b_embed; g1,b1)
//   3x GAT: h = x@Wl+bl; attn = softmax(h h^T / 16); o = attn@h;
//           x = elu(LN(o; gl,btl)); attn recorded
//   out = LN(x @ w_out + b_out; g2,b2); final_attention = mean(attns)
//
// R14 post-mortem: all major lever classes nulled; residual = 5 exchanges +
// ~30 block syncs + launch. R15 trims: (1) Gram-consume relayout to
// (r=tid>>4, j=tid&15) so softmax runs via shfl in the same region (saves a
// sync + LDS RT per layer); (2) out-GEMM does all 3 col-groups in one Pb
// pass (saves 4 syncs); (3) widened final write. Protocol unchanged (proven
// R6-R14): relaxed agent-scope write-through publish + cached first-touch
// consume; per-WG flag barriers; flags zeroed via in-graph memsetAsync.

#define NWG 32

__device__ __forceinline__ void astore(float* p, float v) {
  __hip_atomic_store(p, v, __ATOMIC_RELAXED, __HIP_MEMORY_SCOPE_AGENT);
}

__device__ __forceinline__ void bar_arrive(int* flags, int slot, int w) {
  asm volatile("s_waitcnt vmcnt(0)" ::: "memory");
  __syncthreads();
  if (threadIdx.x == 0)
    __hip_atomic_store(&flags[slot * NWG + w], 1, __ATOMIC_RELAXED,
                       __HIP_MEMORY_SCOPE_AGENT);
}

__device__ __forceinline__ void bar_wait(int* flags, int slot) {
  if (threadIdx.x < NWG) {
    while (__hip_atomic_load(&flags[slot * NWG + threadIdx.x],
                             __ATOMIC_RELAXED,
                             __HIP_MEMORY_SCOPE_AGENT) == 0)
      __builtin_amdgcn_s_sleep(1);
  }
  __syncthreads();
  asm volatile("" ::: "memory");
}

__global__ __launch_bounds__(1024) void sdg_fused(
    const float* __restrict__ feat, const float* __restrict__ w_embed,
    const float* __restrict__ b_embed, const float* __restrict__ g1,
    const float* __restrict__ b1, const float* __restrict__ gat_W,
    const float* __restrict__ gat_b, const float* __restrict__ gat_g,
    const float* __restrict__ gat_bt, const float* __restrict__ w_out,
    const float* __restrict__ b_out, const float* __restrict__ g2,
    const float* __restrict__ b2, float* __restrict__ out, int* flags,
    float* __restrict__ e_ws, float* __restrict__ h_ws,
    float* __restrict__ gp_ws, float* __restrict__ st1_ws,
    float* __restrict__ st2_ws) {
  const int w = blockIdx.x, tid = threadIdx.x;
  const int w8 = w * 8, w24 = w * 24;
  const int c = tid & 7;            // col in slice (8)
  const int ksl = (tid >> 3) & 31;  // k slice (32)
  const int rg = tid >> 8;          // row group (4)
  const int t2 = tid & 255;         // column index for PV/elu

  __shared__ __align__(16) float SA[6912];   // W: [768][9] / [256][9] / 3x
  __shared__ __align__(16) float SB[10752];  // Fs[14][768]; then Xs[14][260]
  __shared__ __align__(16) float Pb[10848];  // partials [32][339] (out) /
                                             // [32][113] (embed, GAT)
  __shared__ float Hb[126];                  // own h block [14][9]
  __shared__ float Gm[224];                  // UNSCALED Gram [14][16]
  __shared__ float Asm[224];                 // probs [14][16], cols 14/15 = 0
  __shared__ float aRow[224];                // attn accumulator
  __shared__ float hm[16];                   // h row means (pads 0)
  __shared__ float Ov[350];                  // own out cols [14][25]
  __shared__ float psg[42], qsg[42];         // out-stage group stats [3][14]
  __shared__ float Mn[14], Rs[14];

  float* const Fs = SB;  // [14][768] during embed
  float* const Xs = SB;  // [14][260] afterwards

  // ---- stage embed weights -> SA[768][9] + feat ----
#pragma unroll
  for (int i = 0; i < 2; ++i) {
    const int idx = i * 1024 + tid;  // 1536 float4 slots
    if (idx < 1536) {
      const int k = idx >> 1, q = (idx & 1) * 4;
      const float4 v = *(const float4*)(&w_embed[k * 256 + w8 + q]);
      SA[k * 9 + q + 0] = v.x;
      SA[k * 9 + q + 1] = v.y;
      SA[k * 9 + q + 2] = v.z;
      SA[k * 9 + q + 3] = v.w;
    }
  }
  for (int i = tid; i < 2688; i += 1024)
    *(float4*)(&Fs[i * 4]) = ((const float4*)feat)[i];
  if (tid < 224) aRow[tid] = 0.f;
  if (tid < 28) Asm[(tid >> 1) * 16 + 14 + (tid & 1)] = 0.f;  // pad cols
  if (tid < 2) hm[14 + tid] = 0.f;
  __syncthreads();

  // ---- S0: embed GEMM (4 rows x 24 k x 8 cols per thread) ----
  {
    float acc[4] = {0.f, 0.f, 0.f, 0.f};
    const int r0 = rg * 4, kb = ksl * 24;
#pragma unroll
    for (int ch = 0; ch < 6; ++ch) {
      const int k = kb + ch * 4;
      const float w0 = SA[(k + 0) * 9 + c];
      const float w1 = SA[(k + 1) * 9 + c];
      const float w2 = SA[(k + 2) * 9 + c];
      const float w3 = SA[(k + 3) * 9 + c];
#pragma unroll
      for (int rr = 0; rr < 4; ++rr) {
        const int r = r0 + rr;
        if (r < 14) {
          const float4 xv = *(const float4*)(&Fs[r * 768 + k]);
          acc[rr] = fmaf(
              xv.x, w0, fmaf(xv.y, w1, fmaf(xv.z, w2, fmaf(xv.w, w3, acc[rr]))));
        }
      }
    }
#pragma unroll
    for (int rr = 0; rr < 4; ++rr) {
      const int r = r0 + rr;
      if (r < 14) Pb[ksl * 113 + r * 8 + c] = acc[rr];
    }
  }
  __syncthreads();
  // column reduce + publish e + LN1 partial stats (8-col sum/sumsq)
  if (tid < 112) {
    const int r = tid >> 3, cc = tid & 7;
    float v = b_embed[w8 + cc];
#pragma unroll
    for (int q = 0; q < 32; ++q) v += Pb[q * 113 + tid];
    astore(&e_ws[r * 256 + w8 + cc], v);
    float sv = v, sq = v * v;
#pragma unroll
    for (int off = 4; off; off >>= 1) {
      sv += __shfl_xor(sv, off, 8);
      sq += __shfl_xor(sq, off, 8);
    }
    if (cc == 0) {
      astore(&st1_ws[w * 28 + r], sv);
      astore(&st1_ws[w * 28 + 14 + r], sq);
    }
  }
  bar_arrive(flags, 0, w);
  // stage layer-0 GAT weights [256][9] under the barrier wait
  if (tid < 512) {
    const int k = tid >> 1, q = (tid & 1) * 4;
    const float4 v = *(const float4*)(&gat_W[k * 256 + w8 + q]);
    SA[k * 9 + q + 0] = v.x;
    SA[k * 9 + q + 1] = v.y;
    SA[k * 9 + q + 2] = v.z;
    SA[k * 9 + q + 3] = v.w;
  }
  bar_wait(flags, 0);

  // ---- LN1 from stats (width-32 consume) + stage e -> Xs ----
  if (tid < 448) {
    const int r = tid >> 5, seg = tid & 31;
    float S = st1_ws[seg * 28 + r];
    float Q = st1_ws[seg * 28 + 14 + r];
#pragma unroll
    for (int off = 16; off; off >>= 1) {
      S += __shfl_xor(S, off, 32);
      Q += __shfl_xor(Q, off, 32);
    }
    if (seg == 0) {
      const float m = S * (1.f / 256.f);
      Mn[r] = m;
      Rs[r] = rsqrtf(Q * (1.f / 256.f) - m * m + 1e-5f);
    }
  }
  if (tid < 896) {
    const float4 v = ((const float4*)e_ws)[tid];
    const int idx = tid * 4, r = idx >> 8, cc = idx & 255;
    *(float4*)(&Xs[r * 260 + cc]) = v;
  }
  __syncthreads();
  for (int i = tid; i < 3584; i += 1024) {
    const int r = i >> 8, cc = i & 255;
    Xs[r * 260 + cc] = (Xs[r * 260 + cc] - Mn[r]) * Rs[r] * g1[cc] + b1[cc];
  }
  __syncthreads();

  // ---- 3 GAT layers, one barrier each ----
  for (int l = 0; l < 3; ++l) {
    // GEMM: 4 rows x 8 k x 8 cols per thread
    {
      float acc[4] = {0.f, 0.f, 0.f, 0.f};
      const int r0 = rg * 4, kb = ksl * 8;
#pragma unroll
      for (int ch = 0; ch < 2; ++ch) {
        const int k = kb + ch * 4;
        const float w0 = SA[(k + 0) * 9 + c];
        const float w1 = SA[(k + 1) * 9 + c];
        const float w2 = SA[(k + 2) * 9 + c];
        const float w3 = SA[(k + 3) * 9 + c];
#pragma unroll
        for (int rr = 0; rr < 4; ++rr) {
          const int r = r0 + rr;
          if (r < 14) {
            const float4 xv = *(const float4*)(&Xs[r * 260 + k]);
            acc[rr] = fmaf(
                xv.x, w0,
                fmaf(xv.y, w1, fmaf(xv.z, w2, fmaf(xv.w, w3, acc[rr]))));
          }
        }
      }
#pragma unroll
      for (int rr = 0; rr < 4; ++rr) {
        const int r = r0 + rr;
        if (r < 14) Pb[ksl * 113 + r * 8 + c] = acc[rr];
      }
    }
    __syncthreads();
    // reduce + publish h + h row-sum partial (for mean identity)
    if (tid < 112) {
      const int r = tid >> 3, cc = tid & 7;
      float v = gat_b[l * 256 + w8 + cc];
#pragma unroll
      for (int q = 0; q < 32; ++q) v += Pb[q * 113 + tid];
      Hb[r * 9 + cc] = v;
      astore(&h_ws[l * 3584 + r * 256 + w8 + cc], v);
      float sv = v;
#pragma unroll
      for (int off = 4; off; off >>= 1) sv += __shfl_xor(sv, off, 8);
      if (cc == 0) astore(&gp_ws[l * 7168 + w * 224 + 196 + r], sv);
    }
    __syncthreads();
    // partial Gram over own 8 cols
    if (tid < 196) {
      const int i = tid / 14, j = tid - i * 14;
      float s = 0.f;
#pragma unroll
      for (int cc = 0; cc < 8; ++cc)
        s = fmaf(Hb[i * 9 + cc], Hb[j * 9 + cc], s);
      astore(&gp_ws[l * 7168 + w * 224 + tid], s);
    }
    bar_arrive(flags, 1 + l, w);
    // stage next-stage weights into SA under the barrier wait
    if (l < 2) {
      if (tid < 512) {
        const float* Wn = gat_W + (l + 1) * 65536;
        const int k = tid >> 1, q = (tid & 1) * 4;
        const float4 v = *(const float4*)(&Wn[k * 256 + w8 + q]);
        SA[k * 9 + q + 0] = v.x;
        SA[k * 9 + q + 1] = v.y;
        SA[k * 9 + q + 2] = v.z;
        SA[k * 9 + q + 3] = v.w;
      }
    } else {
      if (tid < 512) {
        const int k = tid >> 1, q = (tid & 1) * 4;
#pragma unroll
        for (int g = 0; g < 3; ++g) {
          const float4 v = *(const float4*)(&w_out[k * 768 + w24 + g * 8 + q]);
          SA[g * 2304 + k * 9 + q + 0] = v.x;
          SA[g * 2304 + k * 9 + q + 1] = v.y;
          SA[g * 2304 + k * 9 + q + 2] = v.z;
          SA[g * 2304 + k * 9 + q + 3] = v.w;
        }
      }
    }
    bar_wait(flags, 1 + l);

    // issue PV h loads FIRST (in flight during consume + softmax)
    float hv[16];
    hv[14] = 0.f;
    hv[15] = 0.f;
#pragma unroll
    for (int m = 0; m < 14; ++m) hv[m] = h_ws[l * 3584 + m * 256 + t2];
    // FUSED consume + softmax: 15 x 16-lane groups (row r in one group)
    if (tid < 240) {
      const int r = tid >> 4, j = tid & 15;
      float s = 0.f;
      if (j < 14) {
        const int off0 = (r < 14) ? (r * 14 + j) : (196 + j);
        const float* gpl = gp_ws + l * 7168 + off0;
#pragma unroll
        for (int ww = 0; ww < 32; ++ww) s += gpl[ww * 224];
      }
      if (r < 14) {
        if (j < 14) Gm[r * 16 + j] = s;  // unscaled Gram
        const float lv = (j < 14) ? s * 0.0625f : -1e30f;  // mask never fires
        float mx = lv;
#pragma unroll
        for (int off2 = 8; off2; off2 >>= 1)
          mx = fmaxf(mx, __shfl_xor(mx, off2, 16));
        float p = (j < 14) ? expf(lv - mx) : 0.f;
        float sm = p;
#pragma unroll
        for (int off2 = 8; off2; off2 >>= 1) sm += __shfl_xor(sm, off2, 16);
        p /= sm;
        if (j < 14) {
          Asm[r * 16 + j] = p;
          aRow[r * 16 + j] += p * (1.f / 3.f);
        }
      } else if (j < 14) {
        hm[j] = s * (1.f / 256.f);
      }
    }
    __syncthreads();
    // PV (all threads) + LN stats from A,G,hm (224 threads, concurrent)
    float o[4] = {0.f, 0.f, 0.f, 0.f};
#pragma unroll
    for (int mc = 0; mc < 4; ++mc) {
#pragma unroll
      for (int rr = 0; rr < 4; ++rr) {
        const int r = rg * 4 + rr;
        if (r < 14) {
          const float4 a = *(const float4*)(&Asm[r * 16 + mc * 4]);
          o[rr] = fmaf(a.x, hv[mc * 4 + 0],
                       fmaf(a.y, hv[mc * 4 + 1],
                            fmaf(a.z, hv[mc * 4 + 2],
                                 fmaf(a.w, hv[mc * 4 + 3], o[rr]))));
        }
      }
    }
    if (tid < 224) {
      const int r = tid >> 4, j = tid & 15;
      const float aj = Asm[r * 16 + j];  // pads are 0
      float tq = 0.f;
      if (j < 14) {
#pragma unroll
        for (int i = 0; i < 14; ++i)
          tq = fmaf(Asm[r * 16 + i], Gm[i * 16 + j], tq);
      }
      float qv = tq * aj;     // A^T G A partial
      float mv = aj * hm[j];  // mean partial
#pragma unroll
      for (int off = 8; off; off >>= 1) {
        qv += __shfl_xor(qv, off, 16);
        mv += __shfl_xor(mv, off, 16);
      }
      if (j == 0) {
        Mn[r] = mv;
        Rs[r] = rsqrtf(qv * (1.f / 256.f) - mv * mv + 1e-5f);
      }
    }
    __syncthreads();
    // LN + elu directly on registers -> Xs
    {
      const float gc = gat_g[l * 256 + t2], bc = gat_bt[l * 256 + t2];
#pragma unroll
      for (int rr = 0; rr < 4; ++rr) {
        const int r = rg * 4 + rr;
        if (r < 14) {
          const float xn = (o[rr] - Mn[r]) * Rs[r] * gc + bc;
          Xs[r * 260 + t2] = xn > 0.f ? xn : expm1f(xn);
        }
      }
      if (l == 2 && w < 14 && tid < 14)
        out[10752 + w * 14 + tid] = aRow[w * 16 + tid];  // final_attention
    }
    __syncthreads();
  }

  // ---- S4: out GEMM, ALL 3 col-groups in one Pb pass ----
  {
    float acc[12];
#pragma unroll
    for (int i = 0; i < 12; ++i) acc[i] = 0.f;
    const int r0 = rg * 4, kb = ksl * 8;
#pragma unroll
    for (int ch = 0; ch < 2; ++ch) {
      const int k = kb + ch * 4;
#pragma unroll
      for (int g = 0; g < 3; ++g) {
        const float w0 = SA[g * 2304 + (k + 0) * 9 + c];
        const float w1 = SA[g * 2304 + (k + 1) * 9 + c];
        const float w2 = SA[g * 2304 + (k + 2) * 9 + c];
        const float w3 = SA[g * 2304 + (k + 3) * 9 + c];
#pragma unroll
        for (int rr = 0; rr < 4; ++rr) {
          const int r = r0 + rr;
          if (r < 14) {
            const float4 xv = *(const float4*)(&Xs[r * 260 + k]);
            acc[g * 4 + rr] = fmaf(
                xv.x, w0,
                fmaf(xv.y, w1,
                     fmaf(xv.z, w2, fmaf(xv.w, w3, acc[g * 4 + rr]))));
          }
        }
      }
    }
#pragma unroll
    for (int g = 0; g < 3; ++g)
#pragma unroll
      for (int rr = 0; rr < 4; ++rr) {
        const int r = r0 + rr;
        if (r < 14) Pb[ksl * 339 + g * 113 + r * 8 + c] = acc[g * 4 + rr];
      }
  }
  __syncthreads();
  if (tid < 384) {
    const int g = tid >> 7, idx = tid & 127;
    if (idx < 112) {
      const int r = idx >> 3, cc = idx & 7;
      float v = b_out[w24 + g * 8 + cc];
#pragma unroll
      for (int q = 0; q < 32; ++q) v += Pb[q * 339 + g * 113 + idx];
      Ov[r * 25 + g * 8 + cc] = v;
      float sv = v, sq = v * v;
#pragma unroll
      for (int off = 4; off; off >>= 1) {
        sv += __shfl_xor(sv, off, 8);
        sq += __shfl_xor(sq, off, 8);
      }
      if (cc == 0) {
        psg[g * 14 + r] = sv;
        qsg[g * 14 + r] = sq;
      }
    }
  }
  __syncthreads();
  if (tid < 14) {
    astore(&st2_ws[w * 28 + tid], psg[tid] + psg[14 + tid] + psg[28 + tid]);
    astore(&st2_ws[w * 28 + 14 + tid],
           qsg[tid] + qsg[14 + tid] + qsg[28 + tid]);
  }
  bar_arrive(flags, 4, w);
  bar_wait(flags, 4);
  // LN768 from stats (width-32 consume); write own 24 output columns
  if (tid < 448) {
    const int r = tid >> 5, seg = tid & 31;
    float S = st2_ws[seg * 28 + r];
    float Q = st2_ws[seg * 28 + 14 + r];
#pragma unroll
    for (int off = 16; off; off >>= 1) {
      S += __shfl_xor(S, off, 32);
      Q += __shfl_xor(Q, off, 32);
    }
    if (seg == 0) {
      const float m = S * (1.f / 768.f);
      Mn[r] = m;
      Rs[r] = rsqrtf(Q * (1.f / 768.f) - m * m + 1e-5f);
    }
  }
  __syncthreads();
  if (tid < 384) {
    const int g = tid >> 7, idx = tid & 127;
    if (idx < 112) {
      const int r = idx >> 3, cc = idx & 7;
      const int col = w24 + g * 8 + cc;
      out[r * 768 + col] =
          (Ov[r * 25 + g * 8 + cc] - Mn[r]) * Rs[r] * g2[col] + b2[col];
    }
  }
}

extern "C" void kernel_launch(void* const* d_in, const int* in_sizes, int n_in,
                              void* d_out, int out_size, void* d_ws,
                              size_t ws_size, hipStream_t stream) {
  const float* feat = (const float*)d_in[0];
  // d_in[1] (bb_coords) provably does not influence the outputs — unused.
  const float* w_embed = (const float*)d_in[2];
  const float* b_embed = (const float*)d_in[3];
  const float* g1 = (const float*)d_in[4];
  const float* b1 = (const float*)d_in[5];
  const float* gat_W = (const float*)d_in[6];
  const float* gat_b = (const float*)d_in[7];
  const float* gat_g = (const float*)d_in[8];
  const float* gat_bt = (const float*)d_in[9];
  const float* w_out = (const float*)d_in[10];
  const float* b_out = (const float*)d_in[11];
  const float* g2 = (const float*)d_in[12];
  const float* b2 = (const float*)d_in[13];
  float* out = (float*)d_out;

  int* flags = (int*)d_ws;           // 5 * 32 flags (160 ints, pad 192)
  float* e_ws = (float*)d_ws + 192;  // 3584
  float* h_ws = e_ws + 3584;         // 3 * 3584
  float* gp_ws = h_ws + 3 * 3584;    // 3 * 32 * 224 (196 gram + 14 hsum)
  float* st1_ws = gp_ws + 3 * 7168;  // 32 * 28 (LN1 stats)
  float* st2_ws = st1_ws + 896;      // 32 * 28 (LN768 stats)

  hipMemsetAsync(flags, 0, 192 * sizeof(int), stream);
  sdg_fused<<<NWG, 1024, 0, stream>>>(feat, w_embed, b_embed, g1, b1, gat_W,
                                      gat_b, gat_g, gat_bt, w_out, b_out, g2,
                                      b2, out, flags, e_ws, h_ws, gp_ws,
                                      st1_ws, st2_ws);
}